// Round 5
// baseline (121.391 us; speedup 1.0000x reference)
//
#include <hip/hip_runtime.h>
#include <hip/hip_fp16.h>

#define SEQ 2048
#define NBH 32
#define C1f 0.09016844005556021f   // log2(e)/16

typedef _Float16 f16x8 __attribute__((ext_vector_type(8)));
typedef __fp16 fp16x2 __attribute__((ext_vector_type(2)));
typedef float f32x4 __attribute__((ext_vector_type(4)));
typedef __attribute__((address_space(1))) const unsigned GASU;
typedef __attribute__((address_space(3))) unsigned LASU;

union U16 { fp16x2 h[4]; f16x8 v; };

__device__ __forceinline__ void gll16(const void* g, void* l) {
  __builtin_amdgcn_global_load_lds((GASU*)g, (LASU*)l, 16, 0, 0);
}

// ---------------- Kernel A: transpose V -> vt[bh][d][s] fp16, + W -> Wt hi/lo fp16 ----------------
__global__ __launch_bounds__(256) void transpose_wt(const float* __restrict__ v,
                                                    const float* __restrict__ Wg,
                                                    __half* __restrict__ vt,
                                                    __half* __restrict__ wth,
                                                    __half* __restrict__ wtl) {
  if (blockIdx.x == SEQ / 64) {           // W prep (one block)
    if (blockIdx.y) return;
    int r = threadIdx.x & 63, dg = threadIdx.x >> 6;
    __half th[16], tl[16];
    #pragma unroll
    for (int j = 0; j < 16; ++j) {
      float w = Wg[(dg * 16 + j) * 64 + r];
      th[j] = __float2half(w);
      tl[j] = __float2half(w - __half2float(th[j]));
    }
    *(uint4*)&wth[r * 64 + dg * 16] = *(uint4*)&th[0];
    *(uint4*)&wth[r * 64 + dg * 16 + 8] = *(uint4*)&th[8];
    *(uint4*)&wtl[r * 64 + dg * 16] = *(uint4*)&tl[0];
    *(uint4*)&wtl[r * 64 + dg * 16 + 8] = *(uint4*)&tl[8];
    return;
  }
  int bh = blockIdx.y;
  int s0 = blockIdx.x * 64;
  __shared__ float t[64][65];
  int tid = threadIdx.x;
  const float* base = v + ((long)bh * SEQ + s0) * 64;
  #pragma unroll
  for (int i = 0; i < 4; ++i) {
    int seg = i * 256 + tid;
    int srow = seg >> 4, sc4 = (seg & 15) << 2;
    float4 x = *(const float4*)(base + srow * 64 + sc4);
    t[srow][sc4 + 0] = x.x; t[srow][sc4 + 1] = x.y;
    t[srow][sc4 + 2] = x.z; t[srow][sc4 + 3] = x.w;
  }
  __syncthreads();
  int d = tid >> 2, sc = (tid & 3) << 4;
  __half tmp[16];
  #pragma unroll
  for (int j = 0; j < 16; ++j) tmp[j] = __float2half(t[sc + j][d]);
  __half* dst = vt + ((long)bh * 64 + d) * SEQ + s0 + sc;
  *(uint4*)dst = *(uint4*)&tmp[0];
  *(uint4*)(dst + 8) = *(uint4*)&tmp[8];
}

// ---------------- Kernel B: MFMA projection -> phi/8 fp16 + ekn = e^{||k||^2/16} ----------------
__global__ __launch_bounds__(256) void proj_phi(
    const float* __restrict__ qg, const float* __restrict__ kg,
    const __half* __restrict__ wth, const __half* __restrict__ wtl,
    const float* __restrict__ bg,
    __half* __restrict__ phiq, __half* __restrict__ phik,
    float* __restrict__ kns) {
  const int wave = threadIdx.x >> 6, lane = threadIdx.x & 63;
  const int g = lane >> 4, ql = lane & 15;
  const int isk = blockIdx.y;
  const float* src = isk ? kg : qg;
  __half* dphi = isk ? phik : phiq;
  const long rowblk = (long)blockIdx.x * 64;

  __shared__ __align__(16) float x_l[64 * 64];

  const float* xb = src + rowblk * 64;
  #pragma unroll
  for (int i = 0; i < 4; ++i) {
    int seg = i * 256 + wave * 64 + lane;
    int row = seg >> 4;
    int off = ((seg & 15) * 4) ^ ((row & 7) << 2);
    gll16(xb + row * 64 + off, &x_l[(i * 256 + wave * 64) * 4]);
  }

  f16x8 bh_[2][4], bl_[2][4];
  #pragma unroll
  for (int rt = 0; rt < 4; ++rt)
    #pragma unroll
    for (int ks = 0; ks < 2; ++ks) {
      bh_[ks][rt] = *(const f16x8*)&wth[(rt * 16 + ql) * 64 + ks * 32 + g * 8];
      bl_[ks][rt] = *(const f16x8*)&wtl[(rt * 16 + ql) * 64 + ks * 32 + g * 8];
    }
  float bias[4];
  #pragma unroll
  for (int rt = 0; rt < 4; ++rt) bias[rt] = bg[rt * 16 + ql];

  __syncthreads();

  const int rl = wave * 16 + ql;
  float xv[16];
  #pragma unroll
  for (int ks = 0; ks < 2; ++ks)
    #pragma unroll
    for (int h = 0; h < 2; ++h) {
      int fi = (rl * 64 + ks * 32 + g * 8 + h * 4) ^ ((ql & 7) << 2);
      f32x4 u = *(const f32x4*)&x_l[fi];
      #pragma unroll
      for (int j = 0; j < 4; ++j) xv[ks * 8 + h * 4 + j] = u[j];
    }
  if (isk) {
    float nn = 0.f;
    #pragma unroll
    for (int j = 0; j < 16; ++j) nn = fmaf(xv[j], xv[j], nn);
    nn += __shfl_xor(nn, 16);
    nn += __shfl_xor(nn, 32);
    if (g == 0) kns[rowblk + rl] = exp2f(nn * C1f);
  }

  f16x8 ah[2], al[2];
  #pragma unroll
  for (int ks = 0; ks < 2; ++ks)
    #pragma unroll
    for (int j = 0; j < 8; ++j) {
      float v = xv[ks * 8 + j];
      _Float16 hv = (_Float16)v;
      ah[ks][j] = hv;
      al[ks][j] = (_Float16)(v - (float)hv);
    }

  f32x4 sacc[4] = {};
  #pragma unroll
  for (int ks = 0; ks < 2; ++ks)
    #pragma unroll
    for (int rt = 0; rt < 4; ++rt) {
      sacc[rt] = __builtin_amdgcn_mfma_f32_16x16x32_f16(ah[ks], bh_[ks][rt], sacc[rt], 0, 0, 0);
      sacc[rt] = __builtin_amdgcn_mfma_f32_16x16x32_f16(al[ks], bh_[ks][rt], sacc[rt], 0, 0, 0);
      sacc[rt] = __builtin_amdgcn_mfma_f32_16x16x32_f16(ah[ks], bl_[ks][rt], sacc[rt], 0, 0, 0);
    }

  #pragma unroll
  for (int rt = 0; rt < 4; ++rt)
    #pragma unroll
    for (int i2 = 0; i2 < 4; ++i2) {
      float wq = sacc[rt][i2] + bias[rt];
      float sv, cv;
      __sincosf(wq, &sv, &cv);
      long row = rowblk + wave * 16 + g * 4 + i2;
      dphi[row * 128 + rt * 16 + ql] = __float2half(cv * 0.125f);
      dphi[row * 128 + 64 + rt * 16 + ql] = __float2half(sv * 0.125f);
    }
}

// ---------------- Kernel C: flash attention; LDS = phik only; P in registers ----------------
__global__ __launch_bounds__(256, 2) void attn_kernel(
    const __half* __restrict__ phiq_g, const __half* __restrict__ phik_g,
    const __half* __restrict__ vt_g, const float* __restrict__ ekn_g,
    float* __restrict__ out) {
  const int x = blockIdx.x;
  const int bh = ((x & 7) << 2) | ((x >> 3) & 3);      // 4 bh per XCD -> L2 locality
  const int braw = x >> 5;
  const int b = (braw < 8) ? (15 - braw) : (braw - 8); // heavy first; CU pairs sum const
  const int wave = threadIdx.x >> 6, lane = threadIdx.x & 63;
  const int g = lane >> 4, ql = lane & 15;
  const long rowbase = (long)bh * SEQ;
  const int qbase = b * 128 + (3 - wave) * 32;

  __shared__ __align__(16) __half phik_l[2][64 * 128]; // 32 KB total; sigma-permuted + swizzled

  const __half* pkb = phik_g + rowbase * 128;
  const __half* vtb = vt_g + (long)bh * 64 * SEQ;
  const float* ekb = ekn_g + rowbase;

  // sigma: LDS row rho=[kt1 kt0 | g1 g0 | r1 r0] holds global key [kt0 | g1 g0 | kt1 | r1 r0]
  auto stage = [&](int t, int bb) {
    const __half* ks = pkb + t * 64 * 128;
    #pragma unroll
    for (int i = 0; i < 4; ++i) {
      int seg = i * 256 + wave * 64 + lane;
      int rho = seg >> 4;
      int sg = ((rho & 16) << 1) | ((rho & 12) << 1) | ((rho & 32) >> 3) | (rho & 3);
      int off = ((seg & 15) * 8) ^ ((rho & 15) << 3);
      gll16(ks + sg * 128 + off, &phik_l[bb][(i * 256 + wave * 64) * 8]);
    }
  };

  stage(0, 0);

  f16x8 bq[2][4];
  #pragma unroll
  for (int c = 0; c < 2; ++c)
    #pragma unroll
    for (int ks = 0; ks < 4; ++ks)
      bq[c][ks] = *(const f16x8*)(phiq_g + (rowbase + qbase + c * 16 + ql) * 128 + ks * 32 + g * 8);

  float M[2] = {0.f, 0.f}, Minv[2] = {0.f, 0.f}, lsum[2] = {0.f, 0.f};
  f32x4 acc[2][4] = {};

  const int ntiles = 2 * b + 2;
  for (int t = 0; t < ntiles; ++t) {
    const int bb = t & 1;
    asm volatile("s_waitcnt vmcnt(0)" ::: "memory");
    __builtin_amdgcn_s_barrier();
    __builtin_amdgcn_sched_barrier(0);
    if (t + 1 < ntiles) stage(t + 1, bb ^ 1);

    const bool skip = (t == 2 * b + 1) && (wave >= 2);   // fully-masked waves on last tile
    if (!skip) {
      // ---- V^T fragments + ekn straight from global (L2-hot), issued early ----
      f16x8 bv[2][4];
      #pragma unroll
      for (int ks2 = 0; ks2 < 2; ++ks2)
        #pragma unroll
        for (int dt = 0; dt < 4; ++dt)
          bv[ks2][dt] = *(const f16x8*)(vtb + (long)(dt * 16 + ql) * SEQ + t * 64 + ks2 * 32 + g * 8);
      const float* ekt = ekb + t * 64 + g * 8;
      f32x4 ek[4];
      ek[0] = *(const f32x4*)(ekt);        // kt=0: keys g*8+r
      ek[2] = *(const f32x4*)(ekt + 4);    // kt=2: keys g*8+4+r
      ek[1] = *(const f32x4*)(ekt + 32);   // kt=1: keys 32+g*8+r
      ek[3] = *(const f32x4*)(ekt + 36);   // kt=3: keys 32+g*8+4+r

      // ---- scores: S^T = phik_tile x phiq^T ----
      f32x4 s0[4] = {}, s1[4] = {};
      __builtin_amdgcn_s_setprio(1);
      #pragma unroll
      for (int ks = 0; ks < 4; ++ks) {
        f16x8 a[4];
        #pragma unroll
        for (int kt = 0; kt < 4; ++kt) {
          int idx = ((kt * 16 + ql) * 128 + ks * 32 + g * 8) ^ (ql << 3);
          a[kt] = *(const f16x8*)&phik_l[bb][idx];
        }
        #pragma unroll
        for (int kt = 0; kt < 4; ++kt)
          s0[kt] = __builtin_amdgcn_mfma_f32_16x16x32_f16(a[kt], bq[0][ks], s0[kt], 0, 0, 0);
        #pragma unroll
        for (int kt = 0; kt < 4; ++kt)
          s1[kt] = __builtin_amdgcn_mfma_f32_16x16x32_f16(a[kt], bq[1][ks], s1[kt], 0, 0, 0);
      }
      __builtin_amdgcn_s_setprio(0);

      f16x8 pa[2][2];   // [chunk][ks2]

      auto transform = [&](f32x4 (&sc)[4], int c) {
        const int qrow = qbase + c * 16 + ql;
        const bool domask = (t * 64 + 63) > (qbase + c * 16);
        float pv[16];
        float tm = 0.f;
        #pragma unroll
        for (int kt = 0; kt < 4; ++kt)
          #pragma unroll
          for (int r = 0; r < 4; ++r) {
            float d = sc[kt][r];
            float pe = fmaf(d, d, 1e-5f) * ek[kt][r];
            if (domask) {
              int key = t * 64 + ((kt & 1) << 5) + (g << 3) + ((kt >> 1) << 2) + r;
              pe = (key <= qrow) ? pe : 0.f;
            }
            pv[kt * 4 + r] = pe;
            tm = fmaxf(tm, pe);
          }
        tm = fmaxf(tm, __shfl_xor(tm, 16));
        tm = fmaxf(tm, __shfl_xor(tm, 32));
        if (__any(tm > M[c] * 16.f)) {                   // defer-rescale
          float mq = __uint_as_float(__float_as_uint(tm) & 0xFF800000u);  // pow2 floor
          float Mn = fmaxf(M[c], mq);
          float nI = __builtin_amdgcn_rcpf(Mn);          // exact for pow2
          float corr = M[c] * nI;
          M[c] = Mn; Minv[c] = nI;
          lsum[c] *= corr;
          float c4[4];
          #pragma unroll
          for (int r = 0; r < 4; ++r) c4[r] = __shfl(corr, (lane & 48) | (g * 4 + r));
          #pragma unroll
          for (int dt = 0; dt < 4; ++dt)
            #pragma unroll
            for (int r = 0; r < 4; ++r) acc[c][dt][r] *= c4[r];
        }
        const float iv = Minv[c];
        float e[16];
        #pragma unroll
        for (int i = 0; i < 16; ++i) e[i] = pv[i] * iv;
        float psA = ((e[0] + e[1]) + (e[2] + e[3])) + ((e[4] + e[5]) + (e[6] + e[7]));
        float psB = ((e[8] + e[9]) + (e[10] + e[11])) + ((e[12] + e[13]) + (e[14] + e[15]));
        float ps = psA + psB;
        ps += __shfl_xor(ps, 16);
        ps += __shfl_xor(ps, 32);
        lsum[c] += ps;
        // PV A-frags directly from own registers (sigma made keys lane-local)
        U16 A0, A1;
        A0.h[0] = __builtin_amdgcn_cvt_pkrtz(e[0], e[1]);
        A0.h[1] = __builtin_amdgcn_cvt_pkrtz(e[2], e[3]);
        A0.h[2] = __builtin_amdgcn_cvt_pkrtz(e[8], e[9]);
        A0.h[3] = __builtin_amdgcn_cvt_pkrtz(e[10], e[11]);
        A1.h[0] = __builtin_amdgcn_cvt_pkrtz(e[4], e[5]);
        A1.h[1] = __builtin_amdgcn_cvt_pkrtz(e[6], e[7]);
        A1.h[2] = __builtin_amdgcn_cvt_pkrtz(e[12], e[13]);
        A1.h[3] = __builtin_amdgcn_cvt_pkrtz(e[14], e[15]);
        pa[c][0] = A0.v;
        pa[c][1] = A1.v;
      };

      transform(s0, 0);
      transform(s1, 1);

      // ---- PV ----
      __builtin_amdgcn_s_setprio(1);
      #pragma unroll
      for (int ks2 = 0; ks2 < 2; ++ks2)
        #pragma unroll
        for (int dt = 0; dt < 4; ++dt) {
          acc[0][dt] = __builtin_amdgcn_mfma_f32_16x16x32_f16(pa[0][ks2], bv[ks2][dt], acc[0][dt], 0, 0, 0);
          acc[1][dt] = __builtin_amdgcn_mfma_f32_16x16x32_f16(pa[1][ks2], bv[ks2][dt], acc[1][dt], 0, 0, 0);
        }
      __builtin_amdgcn_s_setprio(0);
    }
  }

  // ---- epilogue: normalize + store (register/shfl only) ----
  #pragma unroll
  for (int c = 0; c < 2; ++c) {
    #pragma unroll
    for (int r = 0; r < 4; ++r) {
      float ls = __shfl(lsum[c], (lane & 48) | (g * 4 + r));
      float inv = __builtin_amdgcn_rcpf(ls);
      float* o = out + (rowbase + qbase + c * 16 + g * 4 + r) * 64 + ql;
      #pragma unroll
      for (int dt = 0; dt < 4; ++dt) o[dt * 16] = acc[c][dt][r] * inv;
    }
  }
}

extern "C" void kernel_launch(void* const* d_in, const int* in_sizes, int n_in,
                              void* d_out, int out_size, void* d_ws, size_t ws_size,
                              hipStream_t stream) {
  const float* q = (const float*)d_in[0];
  const float* k = (const float*)d_in[1];
  const float* v = (const float*)d_in[2];
  // d_in[3] = causal mask (applied analytically)
  const float* W = (const float*)d_in[4];
  const float* b = (const float*)d_in[5];
  float* out = (float*)d_out;

  char* ws = (char*)d_ws;
  __half* phiq = (__half*)ws;                          // 16 MB
  __half* phik = (__half*)(ws + 16777216);             // 16 MB
  __half* vt = (__half*)(ws + 33554432);               // 8 MB
  float* ekn = (float*)(ws + 41943040);                // 256 KB
  __half* wth = (__half*)(ws + 41943040 + 262144);     // 8 KB
  __half* wtl = wth + 64 * 64;                         // 8 KB

  transpose_wt<<<dim3(SEQ / 64 + 1, NBH), 256, 0, stream>>>(v, W, vt, wth, wtl);
  proj_phi<<<dim3(NBH * SEQ / 64, 2), 256, 0, stream>>>(q, k, wth, wtl, b, phiq, phik, ekn);
  attn_kernel<<<dim3(512), 256, 0, stream>>>(phiq, phik, vt, ekn, out);
}